// Round 1
// baseline (578.579 us; speedup 1.0000x reference)
//
#include <hip/hip_runtime.h>
#include <hip/hip_bf16.h>
#include <stdint.h>
#include <math.h>

#define D_MODEL 1024
#define NH 16
#define HD 64
#define BATCH 4
#define SEQ 2048
#define MTOT (BATCH*SEQ)   // 8192
#define NBH (BATCH*NH)     // 64

typedef __attribute__((ext_vector_type(8))) short short8;   // 8 bf16 (4 VGPRs)
typedef __attribute__((ext_vector_type(4))) float f32x4;

static __device__ __forceinline__ unsigned short f2bf(float f) {
  union { float f; unsigned u; } v; v.f = f;
  unsigned r = v.u + 0x7FFFu + ((v.u >> 16) & 1u);   // RNE
  return (unsigned short)(r >> 16);
}
static __device__ __forceinline__ float bf2f(unsigned short h) {
  union { unsigned u; float f; } v; v.u = ((unsigned)h) << 16;
  return v.f;
}

#define GLOAD16(g, l) __builtin_amdgcn_global_load_lds( \
    (const __attribute__((address_space(1))) unsigned int*)(g), \
    (__attribute__((address_space(3))) unsigned int*)(l), 16, 0, 0)

// ---------------------------------------------------------------------------
// K0: convert x and weights to bf16, build RoPE tables
// ---------------------------------------------------------------------------
__global__ __launch_bounds__(256) void k_prep(
    const float* __restrict__ x, const float* __restrict__ wq,
    const float* __restrict__ wk, const float* __restrict__ wv,
    const float* __restrict__ wo,
    unsigned short* __restrict__ xb, unsigned short* __restrict__ wb,
    float* __restrict__ cosT, float* __restrict__ sinT) {
  long i = (long)blockIdx.x * 256 + threadIdx.x;
  const long NX = (long)MTOT * D_MODEL;      // 8388608
  const long NW = (long)D_MODEL * D_MODEL;   // 1048576
  if (i < NX) { xb[i] = f2bf(x[i]); return; }
  i -= NX;
  if (i < NW) { wb[i] = f2bf(wq[i]); return; }
  i -= NW;
  if (i < NW) { wb[NW + i] = f2bf(wk[i]); return; }
  i -= NW;
  if (i < NW) { wb[2 * NW + i] = f2bf(wv[i]); return; }
  i -= NW;
  if (i < NW) { wb[3 * NW + i] = f2bf(wo[i]); return; }
  i -= NW;
  if (i < (long)SEQ * (HD / 2)) {
    int t = (int)(i >> 5), j = (int)(i & 31);
    float freq = 1.0f / powf(10000.0f, (float)j * (1.0f / 32.0f));
    float ang = (float)t * freq;
    cosT[i] = cosf(ang);
    sinT[i] = sinf(ang);
  }
}

// ---------------------------------------------------------------------------
// GEMM: C[m][n] = sum_k A[m][k] * Bw[n][k]   (both row-major, K contiguous)
// 128x128 tile, BK=32, 4 waves (2x2 of 64x64), 16x16x32 bf16 MFMA.
// EPI=0: scatter into q/k/v [bh][t][d] bf16.  EPI=1: fp32 out [m][n].
// ---------------------------------------------------------------------------
template<int EPI>
__global__ __launch_bounds__(256) void k_gemm(
    const unsigned short* __restrict__ A, const unsigned short* __restrict__ Bw,
    unsigned short* __restrict__ q, unsigned short* __restrict__ k2,
    unsigned short* __restrict__ v, float* __restrict__ outf) {
  __shared__ __align__(16) unsigned short As[128 * 32];
  __shared__ __align__(16) unsigned short Bs[128 * 32];
  const int tid = threadIdx.x;
  const int wid = tid >> 6, lane = tid & 63;
  const int l15 = lane & 15, lq = lane >> 4;
  const int m0 = blockIdx.x * 128, n0 = blockIdx.y * 128;
  const int wm = (wid >> 1) * 64, wn = (wid & 1) * 64;

  const f32x4 fz = {0.f, 0.f, 0.f, 0.f};
  f32x4 acc[4][4];
#pragma unroll
  for (int i = 0; i < 4; ++i)
#pragma unroll
    for (int j = 0; j < 4; ++j) acc[i][j] = fz;

  // staging: thread -> (row = wid*16 + lane/4 (+64), col = (lane%4)*8), 16B each
  const int srow = wid * 16 + (lane >> 2);
  const int scol = (lane & 3) * 8;
  const unsigned short* Ag = A + (long)(m0 + srow) * D_MODEL + scol;
  const unsigned short* Bg = Bw + (long)(n0 + srow) * D_MODEL + scol;

  for (int k0 = 0; k0 < D_MODEL; k0 += 32) {
    GLOAD16(Ag + k0, As + wid * 512);
    GLOAD16(Ag + k0 + 64 * D_MODEL, As + 2048 + wid * 512);
    GLOAD16(Bg + k0, Bs + wid * 512);
    GLOAD16(Bg + k0 + 64 * D_MODEL, Bs + 2048 + wid * 512);
    __syncthreads();   // drains vmcnt (global_load_lds) + lgkmcnt

    short8 af[4], bf[4];
#pragma unroll
    for (int i = 0; i < 4; ++i) {
      af[i] = *(const short8*)(As + (wm + i * 16 + l15) * 32 + lq * 8);
      bf[i] = *(const short8*)(Bs + (wn + i * 16 + l15) * 32 + lq * 8);
    }
#pragma unroll
    for (int i = 0; i < 4; ++i)
#pragma unroll
      for (int j = 0; j < 4; ++j)
        acc[i][j] = __builtin_amdgcn_mfma_f32_16x16x32_bf16(af[i], bf[j], acc[i][j], 0, 0, 0);
    __syncthreads();
  }

  // epilogue: C layout per 16x16 frag: col = lane&15, row = (lane>>4)*4 + r
#pragma unroll
  for (int i = 0; i < 4; ++i) {
#pragma unroll
    for (int j = 0; j < 4; ++j) {
#pragma unroll
      for (int r = 0; r < 4; ++r) {
        const int m = m0 + wm + i * 16 + lq * 4 + r;
        const int n = n0 + wn + j * 16 + l15;
        const float val = acc[i][j][r];
        if (EPI == 0) {
          const int bb = m >> 11, t = m & (SEQ - 1);
          const int sel = n >> 10, nl = n & 1023;
          const int hh = nl >> 6, dd = nl & 63;
          unsigned short* dst = sel == 0 ? q : (sel == 1 ? k2 : v);
          dst[((((long)bb * NH + hh) * SEQ + t) << 6) + dd] = f2bf(val);
        } else {
          outf[(long)m * D_MODEL + n] = val;
        }
      }
    }
  }
}

// ---------------------------------------------------------------------------
// K2: RoPE in place on q and k: pairs (2j, 2j+1) within head dim
// ---------------------------------------------------------------------------
__global__ __launch_bounds__(256) void k_rope(
    unsigned short* __restrict__ q, unsigned short* __restrict__ k,
    const float* __restrict__ cosT, const float* __restrict__ sinT) {
  long i = (long)blockIdx.x * 256 + threadIdx.x;
  const long NP = (long)NBH * SEQ * 32;   // 4194304 pairs per tensor
  unsigned short* buf = (i < NP) ? q : k;
  const long p = (i < NP) ? i : i - NP;
  const int j = (int)(p & 31);
  const int t = (int)((p >> 5) & (SEQ - 1));
  const long base = ((p >> 5) << 6) + 2 * j;   // (bh*SEQ + t)*64 + 2j
  const float x1 = bf2f(buf[base]), x2 = bf2f(buf[base + 1]);
  const float c = cosT[t * 32 + j], s = sinT[t * 32 + j];
  buf[base]     = f2bf(x1 * c - x2 * s);
  buf[base + 1] = f2bf(x1 * s + x2 * c);
}

// ---------------------------------------------------------------------------
// K3: transpose V: vt[bh][d][t] = v[bh][t][d]
// ---------------------------------------------------------------------------
__global__ __launch_bounds__(256) void k_transpose(
    const unsigned short* __restrict__ v, unsigned short* __restrict__ vt) {
  __shared__ unsigned short tile[32][33];
  const int t0 = blockIdx.x * 32, d0 = blockIdx.y * 32, bh = blockIdx.z;
  const int tx = threadIdx.x & 31, ty = threadIdx.x >> 5;  // ty: 0..7
  const unsigned short* src = v + ((long)bh * SEQ << 6);
#pragma unroll
  for (int i = 0; i < 32; i += 8)
    tile[ty + i][tx] = src[(long)(t0 + ty + i) * HD + d0 + tx];
  __syncthreads();
  unsigned short* dst = vt + (long)bh * HD * SEQ;
#pragma unroll
  for (int i = 0; i < 32; i += 8)
    dst[(long)(d0 + ty + i) * SEQ + t0 + tx] = tile[tx][ty + i];
}

// ---------------------------------------------------------------------------
// K4: causal flash attention. Block = 4 waves; wave = 16 q-rows.
// S = Q K^T via mfma (A=Q frag, B=K frag contiguous 16B); online softmax in
// fp32; P -> bf16 via per-wave LDS transpose; PV via mfma with V^T frags.
// Writes ctx [b][t][h*64+d] bf16.
// ---------------------------------------------------------------------------
__global__ __launch_bounds__(256) void k_attn(
    const unsigned short* __restrict__ qb, const unsigned short* __restrict__ kb,
    const unsigned short* __restrict__ vt, unsigned short* __restrict__ ctx) {
  __shared__ __align__(16) unsigned short P[4][16][32];
  const int wid = threadIdx.x >> 6, lane = threadIdx.x & 63;
  const int l15 = lane & 15, lq = lane >> 4;
  const int bh = blockIdx.y, b = bh >> 4, h = bh & 15;
  const int qrow0 = blockIdx.x * 64 + wid * 16;

  const unsigned short* Qp = qb + (((long)bh * SEQ + qrow0) << 6);
  const short8 aq0 = *(const short8*)(Qp + l15 * HD + lq * 8);
  const short8 aq1 = *(const short8*)(Qp + l15 * HD + 32 + lq * 8);

  const unsigned short* Kp = kb + ((long)bh * SEQ << 6);
  const unsigned short* Vp = vt + (long)bh * HD * SEQ;

  const f32x4 fz = {0.f, 0.f, 0.f, 0.f};
  f32x4 o[4] = {fz, fz, fz, fz};
  float mrow[4] = {-INFINITY, -INFINITY, -INFINITY, -INFINITY};
  float lrow[4] = {0.f, 0.f, 0.f, 0.f};

  const int ntile = (qrow0 + 16 + 31) >> 5;   // causal: kv only up to q-range
  for (int tkv = 0; tkv < ntile; ++tkv) {
    const int kv0 = tkv << 5;
    const unsigned short* kb0 = Kp + ((long)(kv0 + l15) << 6) + lq * 8;
    const short8 bk00 = *(const short8*)(kb0);
    const short8 bk01 = *(const short8*)(kb0 + 32);
    const short8 bk10 = *(const short8*)(kb0 + (16 << 6));
    const short8 bk11 = *(const short8*)(kb0 + (16 << 6) + 32);
    f32x4 s0 = fz, s1 = fz;
    s0 = __builtin_amdgcn_mfma_f32_16x16x32_bf16(aq0, bk00, s0, 0, 0, 0);
    s0 = __builtin_amdgcn_mfma_f32_16x16x32_bf16(aq1, bk01, s0, 0, 0, 0);
    s1 = __builtin_amdgcn_mfma_f32_16x16x32_bf16(aq0, bk10, s1, 0, 0, 0);
    s1 = __builtin_amdgcn_mfma_f32_16x16x32_bf16(aq1, bk11, s1, 0, 0, 0);

    const int kvc0 = kv0 + l15, kvc1 = kvc0 + 16;
    float tm[4], rs[4], al[4];
#pragma unroll
    for (int r = 0; r < 4; ++r) {
      const int qg = qrow0 + lq * 4 + r;
      float v0 = s0[r] * 0.125f; if (kvc0 > qg) v0 = -INFINITY;
      float v1 = s1[r] * 0.125f; if (kvc1 > qg) v1 = -INFINITY;
      s0[r] = v0; s1[r] = v1;
      tm[r] = fmaxf(v0, v1);
    }
#pragma unroll
    for (int off = 1; off < 16; off <<= 1)
#pragma unroll
      for (int r = 0; r < 4; ++r)
        tm[r] = fmaxf(tm[r], __shfl_xor(tm[r], off));
#pragma unroll
    for (int r = 0; r < 4; ++r) {
      const float mn = fmaxf(mrow[r], tm[r]);
      al[r] = __expf(mrow[r] - mn);   // -inf - finite -> 0, no NaN
      mrow[r] = mn;
      const float p0 = __expf(s0[r] - mn);
      const float p1 = __expf(s1[r] - mn);
      s0[r] = p0; s1[r] = p1;
      rs[r] = p0 + p1;
    }
#pragma unroll
    for (int off = 1; off < 16; off <<= 1)
#pragma unroll
      for (int r = 0; r < 4; ++r)
        rs[r] += __shfl_xor(rs[r], off);
#pragma unroll
    for (int r = 0; r < 4; ++r) {
      lrow[r] = lrow[r] * al[r] + rs[r];
      o[0][r] *= al[r]; o[1][r] *= al[r]; o[2][r] *= al[r]; o[3][r] *= al[r];
      P[wid][lq * 4 + r][l15]      = f2bf(s0[r]);
      P[wid][lq * 4 + r][16 + l15] = f2bf(s1[r]);
    }
    // per-wave LDS transpose: read P as MFMA A-fragment (compiler inserts lgkmcnt)
    const short8 pa = *(const short8*)(&P[wid][l15][lq * 8]);
    const unsigned short* vb0 = Vp + (long)l15 * SEQ + kv0 + lq * 8;
    o[0] = __builtin_amdgcn_mfma_f32_16x16x32_bf16(pa, *(const short8*)(vb0), o[0], 0, 0, 0);
    o[1] = __builtin_amdgcn_mfma_f32_16x16x32_bf16(pa, *(const short8*)(vb0 + 16 * SEQ), o[1], 0, 0, 0);
    o[2] = __builtin_amdgcn_mfma_f32_16x16x32_bf16(pa, *(const short8*)(vb0 + 32 * SEQ), o[2], 0, 0, 0);
    o[3] = __builtin_amdgcn_mfma_f32_16x16x32_bf16(pa, *(const short8*)(vb0 + 48 * SEQ), o[3], 0, 0, 0);
  }

  unsigned short* cb = ctx + (((long)b * SEQ) << 10) + (h << 6);
#pragma unroll
  for (int r = 0; r < 4; ++r) {
    const float inv = 1.0f / lrow[r];
    const long t = qrow0 + lq * 4 + r;
#pragma unroll
    for (int dt = 0; dt < 4; ++dt)
      cb[t * D_MODEL + dt * 16 + l15] = f2bf(o[dt][r] * inv);
  }
}

// ---------------------------------------------------------------------------
extern "C" void kernel_launch(void* const* d_in, const int* in_sizes, int n_in,
                              void* d_out, int out_size, void* d_ws, size_t ws_size,
                              hipStream_t stream) {
  const float* x  = (const float*)d_in[0];
  const float* wq = (const float*)d_in[1];
  const float* wk = (const float*)d_in[2];
  const float* wv = (const float*)d_in[3];
  const float* wo = (const float*)d_in[4];
  float* out = (float*)d_out;
  char* ws = (char*)d_ws;

  // workspace layout (total ~88.5 MB)
  unsigned short* xb  = (unsigned short*)(ws);                 // 16 MB (x bf16; reused as ctx)
  unsigned short* wb  = (unsigned short*)(ws + (16l << 20));   // 8 MB  (Wq|Wk|Wv|Wo bf16)
  unsigned short* qb  = (unsigned short*)(ws + (24l << 20));   // 16 MB [bh][t][d]
  unsigned short* kb  = (unsigned short*)(ws + (40l << 20));   // 16 MB
  unsigned short* vb  = (unsigned short*)(ws + (56l << 20));   // 16 MB
  unsigned short* vt  = (unsigned short*)(ws + (72l << 20));   // 16 MB [bh][d][t]
  float* cosT = (float*)(ws + (88l << 20));                    // 256 KB
  float* sinT = cosT + SEQ * 32;                               // 256 KB
  unsigned short* ctx = xb;   // xb is dead after the QKV GEMM

  const long ntot = (long)MTOT * D_MODEL + 4l * D_MODEL * D_MODEL + (long)SEQ * 32;
  k_prep<<<dim3((unsigned)((ntot + 255) / 256)), dim3(256), 0, stream>>>(
      x, wq, wk, wv, wo, xb, wb, cosT, sinT);
  k_gemm<0><<<dim3(64, 24), dim3(256), 0, stream>>>(xb, wb, qb, kb, vb, nullptr);
  k_rope<<<dim3(32768), dim3(256), 0, stream>>>(qb, kb, cosT, sinT);
  k_transpose<<<dim3(64, 2, 64), dim3(256), 0, stream>>>(vb, vt);
  k_attn<<<dim3(32, 64), dim3(256), 0, stream>>>(qb, kb, vt, ctx);
  k_gemm<1><<<dim3(64, 8), dim3(256), 0, stream>>>(
      ctx, wb + 3l * D_MODEL * D_MODEL, nullptr, nullptr, nullptr, out);
}